// Round 11
// baseline (175.057 us; speedup 1.0000x reference)
//
#include <hip/hip_runtime.h>

#define TT 1024
#define CC 128
#define LL 128
#define EPSF 1e-7f
#define LN2F 0.69314718055994531f

#define LOG2F(x) __builtin_amdgcn_logf(x)

typedef unsigned int uint;

template <int CTRL>
__device__ __forceinline__ int dpp_i(int old_, int x) {
  return __builtin_amdgcn_update_dpp(old_, x, CTRL, 0xf, 0xf, false);
}
// shift a3 to next lane (wave_shr:1); lane 0 receives 0.0 via old-value
__device__ __forceinline__ double dpp_shr1_f64(double x) {
  const int lo = __double2loint(x), hi = __double2hiint(x);
  return __hiloint2double(dpp_i<0x138>(0, hi), dpp_i<0x138>(0, lo));
}

// fp32 -> bf16 bits, round-to-nearest-even (inputs finite positive)
__device__ __forceinline__ uint bf16bits(float x) {
  uint u = __float_as_uint(x);
  return (u + 0x7fffu + ((u >> 16) & 1u)) >> 16;
}

// ---- prep (parallel): normalized emission probs, transposed for the scan ----
// PROVEN version (rounds 8-9, absmax 0.0). Block = 512 threads = 8 waves;
// block handles (b, 8 consecutive t).
//   ET[b][t4][L] (uint4 over t in group-of-4: bf16 p[lab 2L] | p[lab 2L+1])
//   EB[b][t] (fp32 blank prob)
__global__ __launch_bounds__(512) void prep_kernel(const int* __restrict__ yt,
                                                   const float* __restrict__ yp,
                                                   uint* __restrict__ ET,
                                                   float* __restrict__ EB) {
  const int tid = threadIdx.x;
  const int w = tid >> 6;  // wave 0..7
  const int L = tid & 63;
  const int b = blockIdx.x >> 7;
  const int tg = blockIdx.x & 127;
  const int t = tg * 8 + w;

  __shared__ float rowp[8][130];  // normalized probs per wave-row
  __shared__ uint tp[64][9];      // [L][w] transpose buffer (+1 pad)

  const float* P = yp + ((size_t)b * TT + t) * CC;
  const float2 v = *(const float2*)(P + 2 * L);
  float x = (v.x + EPSF) + (v.y + EPSF);
#pragma unroll
  for (int off = 32; off > 0; off >>= 1) x += __shfl_xor(x, off);
  const float r = 1.0f / x;
  const float er = EPSF * r;
  *(float2*)&rowp[w][2 * L] =
      make_float2(__builtin_fmaf(v.x, r, er), __builtin_fmaf(v.y, r, er));
  const int2 lab = *(const int2*)(yt + b * LL + 2 * L);
  if (L == 63) EB[b * TT + t] = __builtin_fmaf(v.y, r, er);  // c=127 blank
  __syncthreads();
  const float p1 = rowp[w][lab.x];
  const float p2 = rowp[w][lab.y];
  tp[L][w] = (bf16bits(p2) << 16) | bf16bits(p1);
  __syncthreads();
  if (tid < 128) {  // 2 t4-groups x 64 lanes, coalesced uint4 stores
    const int g4 = tid >> 6, Lo = tid & 63;
    uint4 val;
    val.x = tp[Lo][g4 * 4 + 0];
    val.y = tp[Lo][g4 * 4 + 1];
    val.z = tp[Lo][g4 * 4 + 2];
    val.w = tp[Lo][g4 * 4 + 3];
    ((uint4*)ET)[((size_t)(b * 256 + tg * 2 + g4) << 6) + Lo] = val;
  }
}

// ---- serial scan: fp64 linear-domain scaled forward, one wave per b ----
// Round 9 scan with ONE change: p1/p2 built by exact integer construct
// bf16->f64 (hi word = (u<<13) + 0x38000000, exponent rebias 127->1023;
// exact for positive normal bf16 — all our probs are >= eps/sum ~ 1.5e-9).
// Removes 2 of 3 per-step v_cvt_f64_f32. pb stays f32 + per-step cvt
// (off the critical path; ring stays float4 -> SGPRs).

#define CTC_STEP(wv, pbf)                                                   \
  do {                                                                      \
    const double p1 =                                                       \
        __hiloint2double((int)((((wv)&0xffffu) << 13) + 0x38000000u), 0);   \
    const double p2 =                                                       \
        __hiloint2double((int)((((wv) >> 16) << 13) + 0x38000000u), 0);     \
    const double pb = (double)(pbf);                                        \
    const double p3 = dpp_shr1_f64(a3);                                     \
    const double n0 = (a0 + p3) * pb;                                       \
    const double n1 = fma(s1d, p3, a0 + a1) * p1;                           \
    const double n2 = (a2 + a1) * pb;                                       \
    const double n3 = fma(s3d, a1, a3 + a2) * p2;                           \
    const double n4 = (a4 + a3) * pb;                                       \
    a0 = n0; a1 = n1; a2 = n2; a3 = n3; a4 = n4;                            \
  } while (0)

#define CTC_GROUP(g)                           \
  do {                                         \
    CTC_STEP(et##g.x, eb##g.x);                \
    CTC_STEP(et##g.y, eb##g.y);                \
    CTC_STEP(et##g.z, eb##g.z);                \
    CTC_STEP(et##g.w, eb##g.w);                \
    const int t4n = min(tb4 + 8 + g, 255);     \
    et##g = Et[(size_t)t4n * 64];              \
    eb##g = *(const float4*)(Bp + t4n * 4);    \
  } while (0)

#define CTC_RESCALE()                                             \
  do {                                                            \
    const double m = fmax(fmax(fmax(a0, a1), fmax(a2, a3)), a4);  \
    int ke = (__double2hiint(m) >> 20) & 0x7ff;                   \
    ke = max(ke, dpp_i<0x111>(ke, ke));                           \
    ke = max(ke, dpp_i<0x112>(ke, ke));                           \
    ke = max(ke, dpp_i<0x114>(ke, ke));                           \
    ke = max(ke, dpp_i<0x118>(ke, ke));                           \
    ke = max(ke, dpp_i<0x142>(ke, ke));                           \
    ke = max(ke, dpp_i<0x143>(ke, ke));                           \
    ke = __builtin_amdgcn_readlane(ke, 63);                       \
    const int e = ke - 1534; /* unbiased_exp(max) - 511 */        \
    const double sc = __hiloint2double((1023 - e) << 20, 0);      \
    a0 *= sc; a1 *= sc; a2 *= sc; a3 *= sc; a4 *= sc;             \
    ell += e;                                                     \
  } while (0)

__global__ __launch_bounds__(64) void scan_kernel(const int* __restrict__ yt,
                                                  const uint* __restrict__ ET,
                                                  const float* __restrict__ EB,
                                                  float* __restrict__ out) {
  const int b = blockIdx.x;
  const int L = threadIdx.x & 63;

  const int2 lab = *(const int2*)(yt + b * LL + 2 * L);
  const int labm1 = __shfl_up(lab.y, 1);
  const double s1d = ((L > 0) && (lab.x != labm1)) ? 1.0 : 0.0;  // s=4L+1
  const double s3d = (lab.y != lab.x) ? 1.0 : 0.0;               // s=4L+3

  const uint4* Et = (const uint4*)ET + ((size_t)b << 14) + L;  // [t4][64]
  const float* Bp = EB + b * TT;

  uint4 et0 = Et[0 * 64], et1 = Et[1 * 64], et2 = Et[2 * 64], et3 = Et[3 * 64];
  uint4 et4 = Et[4 * 64], et5 = Et[5 * 64], et6 = Et[6 * 64], et7 = Et[7 * 64];
  float4 eb0 = *(const float4*)(Bp + 0), eb1 = *(const float4*)(Bp + 4);
  float4 eb2 = *(const float4*)(Bp + 8), eb3 = *(const float4*)(Bp + 12);
  float4 eb4 = *(const float4*)(Bp + 16), eb5 = *(const float4*)(Bp + 20);
  float4 eb6 = *(const float4*)(Bp + 24), eb7 = *(const float4*)(Bp + 28);

  // virtual alpha_{-1}: state 0 = 1, rest 0; first loop step yields alpha_0
  double a0 = (L == 0) ? 1.0 : 0.0;
  double a1 = 0.0, a2 = 0.0, a3 = 0.0, a4 = 0.0;
  int ell = 0;  // wave-uniform: alpha_true = a * 2^ell

#pragma unroll 1
  for (int tb4 = 0; tb4 < TT / 4; tb4 += 8) {
    CTC_GROUP(0);
    CTC_GROUP(1);
    CTC_GROUP(2);
    CTC_GROUP(3);
    CTC_RESCALE();
    CTC_GROUP(4);
    CTC_GROUP(5);
    CTC_GROUP(6);
    CTC_GROUP(7);
    CTC_RESCALE();
  }

  if (L == 63) {
    // states 255 (=a3), 256 (=a4): loglik = ln2 * (ell + log2(a3+a4))
    double s = a3 + a4;
    if (s < 2.3e-308) s = 2.3e-308;  // stay normal; loud-but-finite floor
    const int es = ((__double2hiint(s) >> 20) & 0x7ff) - 1023;
    const double mant = s * __hiloint2double((1023 - es) << 20, 0);  // [1,2)
    out[b] = -LN2F * ((float)(ell + es) + LOG2F((float)mant));
  }
}

extern "C" void kernel_launch(void* const* d_in, const int* in_sizes, int n_in,
                              void* d_out, int out_size, void* d_ws,
                              size_t ws_size, hipStream_t stream) {
  const int* yt = (const int*)d_in[0];
  const float* yp = (const float*)d_in[1];
  float* out = (float*)d_out;
  const int B = in_sizes[0] / LL;  // 128
  uint* ET = (uint*)d_ws;                                       // 32 MiB
  float* EB = (float*)((char*)d_ws + (size_t)B * 64 * TT * 4);  // +512 KiB
  hipLaunchKernelGGL(prep_kernel, dim3(B * 128), dim3(512), 0, stream, yt, yp,
                     ET, EB);
  hipLaunchKernelGGL(scan_kernel, dim3(B), dim3(64), 0, stream, yt, ET, EB,
                     out);
}